// Round 16
// baseline (339.669 us; speedup 1.0000x reference)
//
#include <hip/hip_runtime.h>
#include <math.h>

#define CH 64
#define S 64
#define S2 (64 * 64)
#define S3 (64 * 64 * 64)

__device__ float WT_buf[CH * CH];  // W transposed: WT[c][o]

// ---------------------------------------------------------------------------
// Kernel 0: transpose W (64x64) into WT_buf.
// ---------------------------------------------------------------------------
__global__ __launch_bounds__(256) void wtrans(const float* __restrict__ W) {
  int i = blockIdx.x * 256 + threadIdx.x;
  int o = i >> 6, c = i & 63;
  WT_buf[c * CH + o] = W[o * CH + c];
}

// ---------------------------------------------------------------------------
// Kernel 1: attn_x — scores -> softmax -> single-pass V-gather -> x (d_ws).
// r15 structure, but phase A split into TWO c-passes so the peak live
// accumulator set is 27 regs instead of 54:
//   A1: K-tap terms only (sC/sXR/sXL).  A2: pe matvec only (spe), Q re-read
//   (L2/L3-warm). r15 evidence: 54 long-lived accumulators get AGPR-parked
// (VGPR_Count 56 but occupancy capped 43% ~ unified-file 106 regs); halving
// the live set should restore 6-8 waves/SIMD of latency hiding.
// Barrier-free, LDS-free, plain launch bounds. One wave per (b,d,h) row.
// ---------------------------------------------------------------------------
__global__ __launch_bounds__(256) void attn_x(const float* __restrict__ Q,
                                              const float* __restrict__ K,
                                              const float* __restrict__ V,
                                              const float* __restrict__ pe,
                                              float* __restrict__ xout) {
  int tid = threadIdx.x;
  int lane = tid & 63;
  int wv = tid >> 6;

  // XCD-aware bijective swizzle (2048 % 8 == 0)
  int raw = blockIdx.x;
  int sw = (raw & 7) * 256 + (raw >> 3);
  int b = sw >> 10;
  int r = sw & 1023;
  int d = r >> 4;                                             // 0..63
  int hu = __builtin_amdgcn_readfirstlane((r & 15) * 4 + wv);  // 0..63, uniform

  size_t bbase = (size_t)b << 24;
  const float* Qb = Q + bbase;
  const float* Kb = K + bbase;
  const float* Vb = V + bbase;
  float* xo = xout + bbase;

  // per-lane x-pad masks for received shuffles
  float lmL = (lane == 0) ? 0.f : 1.f;
  float lmR = (lane == 63) ? 0.f : 1.f;

  // uniform row bases (clamped) + OOB masks
  const float* krow[9];
  const float* vrow[9];
  float okf[9];
#pragma unroll
  for (int dz = 0; dz < 3; ++dz)
#pragma unroll
    for (int dy = 0; dy < 3; ++dy) {
      int rr = dz * 3 + dy;
      int zz = d + dz - 1, yy = hu + dy - 1;
      bool ok = ((unsigned)zz < 64u) & ((unsigned)yy < 64u);
      int zc = zz < 0 ? 0 : (zz > 63 ? 63 : zz);
      int yc = yy < 0 ? 0 : (yy > 63 ? 63 : yy);
      krow[rr] = Kb + zc * S2 + yc * S;
      vrow[rr] = Vb + zc * S2 + yc * S;
      okf[rr] = ok ? 1.f : 0.f;
    }
  int pos = d * S2 + hu * S + lane;

  // ---- Phase A1: K-tap score terms only (27 accumulators live) ----
  float sC[9], sXR[9], sXL[9];
#pragma unroll
  for (int rr = 0; rr < 9; ++rr) { sC[rr] = 0.f; sXR[rr] = 0.f; sXL[rr] = 0.f; }
#pragma unroll 4
  for (int c = 0; c < CH; ++c) {
    int coff = c * S3;
    float q = Qb[coff + pos];
    float rv[9];
#pragma unroll
    for (int rr = 0; rr < 9; ++rr) rv[rr] = krow[rr][coff + lane];
    float qR = __shfl_down(q, 1);  // q of lane+1
    float qL = __shfl_up(q, 1);    // q of lane-1
#pragma unroll
    for (int rr = 0; rr < 9; ++rr) {
      sC[rr]  = fmaf(q,  rv[rr], sC[rr]);
      sXR[rr] = fmaf(qR, rv[rr], sXR[rr]);  // belongs to lane+1's left tap
      sXL[rr] = fmaf(qL, rv[rr], sXL[rr]);  // belongs to lane-1's right tap
    }
  }

  // ---- Phase A2: pe matvec only (spe[27] live; Q re-read, cache-warm) ----
  float spe[27];
#pragma unroll
  for (int t = 0; t < 27; ++t) spe[t] = 0.f;
#pragma unroll 8
  for (int c = 0; c < CH; ++c) {
    float q = Qb[c * S3 + pos];
    const float* pec = pe + c * 27;  // uniform -> scalar loads
#pragma unroll
    for (int t = 0; t < 27; ++t) spe[t] = fmaf(q, pec[t], spe[t]);
  }

  // ---- assemble the 27 tap scores (18 shuffles, once) ----
  float s[27];
#pragma unroll
  for (int rr = 0; rr < 9; ++rr) {
    float lt = __shfl_up(sXR[rr], 1);    // = sum_c q[w]*K[rr][w-1]
    float rt = __shfl_down(sXL[rr], 1);  // = sum_c q[w]*K[rr][w+1]
    s[rr * 3]     = fmaf(lt * lmL, okf[rr], spe[rr * 3]);
    s[rr * 3 + 1] = fmaf(sC[rr],   okf[rr], spe[rr * 3 + 1]);
    s[rr * 3 + 2] = fmaf(rt * lmR, okf[rr], spe[rr * 3 + 2]);
  }

  // ---- softmax over 27 taps (base-2; normalization folded into weights) ----
  const float SC = 0.125f * 1.44269504088896f;
#pragma unroll
  for (int t = 0; t < 27; ++t) s[t] *= SC;
  float m = s[0];
#pragma unroll
  for (int t = 1; t < 27; ++t) m = fmaxf(m, s[t]);
  float sum = 0.f;
#pragma unroll
  for (int t = 0; t < 27; ++t) {
    s[t] = exp2f(s[t] - m);
    sum += s[t];
  }
  float inv = 1.f / sum;

  // ---- weights: fold inv + row mask; pre-shuffle cross weights ----
  float wC[9], sLs[9], sRs[9];
#pragma unroll
  for (int rr = 0; rr < 9; ++rr) {
    float f = inv * okf[rr];  // OOB rows: V-pad = 0 -> weight 0
    float wL = s[rr * 3] * f;
    wC[rr]   = s[rr * 3 + 1] * f;
    float wR = s[rr * 3 + 2] * f;
    sLs[rr] = __shfl_down(wL, 1);  // left-tap weight of lane+1
    sRs[rr] = __shfl_up(wR, 1);    // right-tap weight of lane-1
  }

  // ---- Phase B: single-pass V-gather, store x immediately (2 shuffles/ch) ----
#pragma unroll 2
  for (int c = 0; c < CH; ++c) {
    int coff = c * S3;
    float rv[9];
#pragma unroll
    for (int rr = 0; rr < 9; ++rr) rv[rr] = vrow[rr][coff + lane];
    float own = 0.f, cR = 0.f, cL = 0.f;
#pragma unroll
    for (int rr = 0; rr < 9; ++rr) {
      own = fmaf(wC[rr], rv[rr], own);
      cR  = fmaf(sLs[rr], rv[rr], cR);  // contribution to x of lane+1
      cL  = fmaf(sRs[rr], rv[rr], cL);  // contribution to x of lane-1
    }
    xo[coff + pos] = own + __shfl_up(cR, 1) * lmL + __shfl_down(cL, 1) * lmR;
  }
}

// ---------------------------------------------------------------------------
// Kernel 2: proj — out[o,p] = sum_c WT[c][o] * x[c,p] + bias[o].
// Each wave owns 64 consecutive positions and a PRIVATE LDS panel [64][64]:
// thread t writes slot [c][t] and later re-reads ONLY [c][t] (same address ->
// compiler-ordered, no barriers, conflict-free). o-tiled: acc[16] live only.
// Proven no-spill at ~60us (r12/r14/r15).
// ---------------------------------------------------------------------------
__global__ __launch_bounds__(256) void proj(const float* __restrict__ x,
                                            const float* __restrict__ bias,
                                            float* __restrict__ out) {
  __shared__ float xs[4][CH][64];  // 65.5 KB
  int tid = threadIdx.x, lane = tid & 63, wv = tid >> 6;
  int grp = blockIdx.x * 4 + wv;       // wave index: 0..8191
  int b = grp >> 12;                   // 4096 waves per batch
  int pos = (grp & 4095) << 6;         // 64 consecutive positions per wave
  size_t base = ((size_t)b << 24) + pos + lane;
  const float* xb = x + base;
  float* xw = &xs[wv][0][0];

  // stage this wave's 64 x-rows (coalesced) into the private panel
#pragma unroll 8
  for (int c = 0; c < CH; ++c) xw[c * 64 + lane] = xb[(size_t)c << 18];

  float* outp = out + base;
#pragma unroll 1
  for (int ot = 0; ot < 4; ++ot) {
    float acc[16];
#pragma unroll
    for (int j = 0; j < 16; ++j) acc[j] = 0.f;
#pragma unroll 4
    for (int c = 0; c < CH; ++c) {
      float xc = xw[c * 64 + lane];          // same address this thread wrote
      const float* wr = WT_buf + c * CH + ot * 16;  // uniform -> wide s_load
#pragma unroll
      for (int j = 0; j < 16; ++j) acc[j] = fmaf(wr[j], xc, acc[j]);
    }
#pragma unroll
    for (int j = 0; j < 16; ++j)
      outp[(size_t)(ot * 16 + j) << 18] = acc[j] + bias[ot * 16 + j];
  }
}

// ---------------------------------------------------------------------------
extern "C" void kernel_launch(void* const* d_in, const int* in_sizes, int n_in,
                              void* d_out, int out_size, void* d_ws, size_t ws_size,
                              hipStream_t stream) {
  const float* Q = (const float*)d_in[0];
  const float* K = (const float*)d_in[1];
  const float* V = (const float*)d_in[2];
  const float* pe = (const float*)d_in[3];
  const float* W = (const float*)d_in[4];
  const float* bias = (const float*)d_in[5];
  float* out = (float*)d_out;
  float* xbuf = (float*)d_ws;  // 134 MB scratch: x[b][c][p]

  wtrans<<<16, 256, 0, stream>>>(W);
  attn_x<<<2048, 256, 0, stream>>>(Q, K, V, pe, xbuf);
  proj<<<2048, 256, 0, stream>>>(xbuf, bias, out);
}

// Round 17
// 312.079 us; speedup vs baseline: 1.0884x; 1.0884x over previous
//
#include <hip/hip_runtime.h>
#include <math.h>

#define CH 64
#define S 64
#define S2 (64 * 64)
#define S3 (64 * 64 * 64)

__device__ float WT_buf[CH * CH];  // W transposed: WT[c][o]

// ---------------------------------------------------------------------------
// Kernel 0: transpose W (64x64) into WT_buf.
// ---------------------------------------------------------------------------
__global__ __launch_bounds__(256) void wtrans(const float* __restrict__ W) {
  int i = blockIdx.x * 256 + threadIdx.x;
  int o = i >> 6, c = i & 63;
  WT_buf[c * CH + o] = W[o * CH + c];
}

__device__ __forceinline__ unsigned short f2bf(float f) {  // RNE to bf16
  unsigned int u = __float_as_uint(f);
  return (unsigned short)((u + 0x7FFFu + ((u >> 16) & 1u)) >> 16);
}
__device__ __forceinline__ float bf2f(unsigned short s) {
  return __uint_as_float(((unsigned int)s) << 16);
}

// ---------------------------------------------------------------------------
// Fused kernel: scores -> softmax -> V-gather -> x in wave-private bf16 LDS
// panel -> W-projection -> out. ONE wave per block (64 thr); one (b,d,h) row
// per wave; lane = w. Phase A/B = r15's proven code verbatim. The x panel
// uses the proven per-thread same-address LDS slot trick (thread t only ever
// touches xs[c][t] -> program-ordered, no barriers, no conflicts). bf16 panel
// = 8 KB/wave so LDS never binds occupancy (16 blocks/CU = HW cap).
// Saves vs r15 split: 268 MB x round-trip + proj launch + proj restage.
// ---------------------------------------------------------------------------
__global__ __launch_bounds__(64) void attn_fused(const float* __restrict__ Q,
                                                 const float* __restrict__ K,
                                                 const float* __restrict__ V,
                                                 const float* __restrict__ pe,
                                                 const float* __restrict__ bias,
                                                 float* __restrict__ out) {
  __shared__ unsigned short xs[CH * 64];  // 8192 B, wave-private
  int lane = threadIdx.x;  // 0..63

  // XCD-aware bijective swizzle (8192 % 8 == 0)
  int raw = blockIdx.x;
  int sw = (raw & 7) * 1024 + (raw >> 3);
  int b = sw >> 12;
  int r = sw & 4095;
  int d = r >> 6;   // 0..63, uniform (from blockIdx)
  int h = r & 63;   // 0..63, uniform

  size_t bbase = (size_t)b << 24;
  const float* Qb = Q + bbase;
  const float* Kb = K + bbase;
  const float* Vb = V + bbase;
  float* outb = out + bbase;

  // per-lane x-pad masks for received shuffles
  float lmL = (lane == 0) ? 0.f : 1.f;
  float lmR = (lane == 63) ? 0.f : 1.f;

  // uniform row bases (clamped) + OOB masks
  const float* krow[9];
  const float* vrow[9];
  float okf[9];
#pragma unroll
  for (int dz = 0; dz < 3; ++dz)
#pragma unroll
    for (int dy = 0; dy < 3; ++dy) {
      int rr = dz * 3 + dy;
      int zz = d + dz - 1, yy = h + dy - 1;
      bool ok = ((unsigned)zz < 64u) & ((unsigned)yy < 64u);
      int zc = zz < 0 ? 0 : (zz > 63 ? 63 : zz);
      int yc = yy < 0 ? 0 : (yy > 63 ? 63 : yy);
      krow[rr] = Kb + zc * S2 + yc * S;
      vrow[rr] = Vb + zc * S2 + yc * S;
      okf[rr] = ok ? 1.f : 0.f;
    }
  int pos = d * S2 + h * S + lane;

  float spe[27];  // pe part (always at own lane, unmasked)
  float sC[9], sXR[9], sXL[9];
#pragma unroll
  for (int t = 0; t < 27; ++t) spe[t] = 0.f;
#pragma unroll
  for (int rr = 0; rr < 9; ++rr) { sC[rr] = 0.f; sXR[rr] = 0.f; sXL[rr] = 0.f; }

  // ---- Phase A: scores (2 shuffles per channel) ----
#pragma unroll 4
  for (int c = 0; c < CH; ++c) {
    int coff = c * S3;
    float q = Qb[coff + pos];
    float rv[9];
#pragma unroll
    for (int rr = 0; rr < 9; ++rr) rv[rr] = krow[rr][coff + lane];
    float qR = __shfl_down(q, 1);  // q of lane+1
    float qL = __shfl_up(q, 1);    // q of lane-1
#pragma unroll
    for (int rr = 0; rr < 9; ++rr) {
      sC[rr]  = fmaf(q,  rv[rr], sC[rr]);
      sXR[rr] = fmaf(qR, rv[rr], sXR[rr]);  // belongs to lane+1's left tap
      sXL[rr] = fmaf(qL, rv[rr], sXL[rr]);  // belongs to lane-1's right tap
    }
    const float* pec = pe + c * 27;  // uniform -> scalar loads
#pragma unroll
    for (int t = 0; t < 27; ++t) spe[t] = fmaf(q, pec[t], spe[t]);
  }

  // ---- assemble the 27 tap scores (18 shuffles, once) ----
  float s[27];
#pragma unroll
  for (int rr = 0; rr < 9; ++rr) {
    float lt = __shfl_up(sXR[rr], 1);    // = sum_c q[w]*K[rr][w-1]
    float rt = __shfl_down(sXL[rr], 1);  // = sum_c q[w]*K[rr][w+1]
    s[rr * 3]     = fmaf(lt * lmL, okf[rr], spe[rr * 3]);
    s[rr * 3 + 1] = fmaf(sC[rr],   okf[rr], spe[rr * 3 + 1]);
    s[rr * 3 + 2] = fmaf(rt * lmR, okf[rr], spe[rr * 3 + 2]);
  }

  // ---- softmax over 27 taps (base-2; normalization folded into weights) ----
  const float SC = 0.125f * 1.44269504088896f;
#pragma unroll
  for (int t = 0; t < 27; ++t) s[t] *= SC;
  float m = s[0];
#pragma unroll
  for (int t = 1; t < 27; ++t) m = fmaxf(m, s[t]);
  float sum = 0.f;
#pragma unroll
  for (int t = 0; t < 27; ++t) {
    s[t] = exp2f(s[t] - m);
    sum += s[t];
  }
  float inv = 1.f / sum;

  // ---- weights: fold inv + row mask; pre-shuffle cross weights ----
  float wC[9], sLs[9], sRs[9];
#pragma unroll
  for (int rr = 0; rr < 9; ++rr) {
    float f = inv * okf[rr];  // OOB rows: V-pad = 0 -> weight 0
    float wL = s[rr * 3] * f;
    wC[rr]   = s[rr * 3 + 1] * f;
    float wR = s[rr * 3 + 2] * f;
    sLs[rr] = __shfl_down(wL, 1);  // left-tap weight of lane+1
    sRs[rr] = __shfl_up(wR, 1);    // right-tap weight of lane-1
  }

  // ---- Phase B: single-pass V-gather -> bf16 LDS slot (own lane only) ----
#pragma unroll 2
  for (int c = 0; c < CH; ++c) {
    int coff = c * S3;
    float rv[9];
#pragma unroll
    for (int rr = 0; rr < 9; ++rr) rv[rr] = vrow[rr][coff + lane];
    float own = 0.f, cR = 0.f, cL = 0.f;
#pragma unroll
    for (int rr = 0; rr < 9; ++rr) {
      own = fmaf(wC[rr], rv[rr], own);
      cR  = fmaf(sLs[rr], rv[rr], cR);  // contribution to x of lane+1
      cL  = fmaf(sRs[rr], rv[rr], cL);  // contribution to x of lane-1
    }
    float x_c = own + __shfl_up(cR, 1) * lmL + __shfl_down(cL, 1) * lmR;
    xs[c * 64 + lane] = f2bf(x_c);  // same-address slot, program-ordered
  }

  // ---- Phase P: projection from the LDS panel; o-tiled, acc[16] live ----
#pragma unroll 1
  for (int ot = 0; ot < 4; ++ot) {
    float acc[16];
#pragma unroll
    for (int j = 0; j < 16; ++j) acc[j] = 0.f;
#pragma unroll 4
    for (int c = 0; c < CH; ++c) {
      float xc = bf2f(xs[c * 64 + lane]);        // re-read own slot only
      const float* wr = WT_buf + c * CH + ot * 16;  // uniform -> wide s_load
#pragma unroll
      for (int j = 0; j < 16; ++j) acc[j] = fmaf(wr[j], xc, acc[j]);
    }
#pragma unroll
    for (int j = 0; j < 16; ++j)
      outb[(ot * 16 + j) * S3 + pos] = acc[j] + bias[ot * 16 + j];
  }
}

// ---------------------------------------------------------------------------
extern "C" void kernel_launch(void* const* d_in, const int* in_sizes, int n_in,
                              void* d_out, int out_size, void* d_ws, size_t ws_size,
                              hipStream_t stream) {
  const float* Q = (const float*)d_in[0];
  const float* K = (const float*)d_in[1];
  const float* V = (const float*)d_in[2];
  const float* pe = (const float*)d_in[3];
  const float* W = (const float*)d_in[4];
  const float* bias = (const float*)d_in[5];
  float* out = (float*)d_out;

  wtrans<<<16, 256, 0, stream>>>(W);
  attn_fused<<<8192, 64, 0, stream>>>(Q, K, V, pe, bias, out);
}

// Round 18
// 234.747 us; speedup vs baseline: 1.4470x; 1.3294x over previous
//
#include <hip/hip_runtime.h>
#include <math.h>

#define CH 64
#define S 64
#define S2 (64 * 64)
#define S3 (64 * 64 * 64)

__device__ float WT_buf[CH * CH];  // W transposed: WT[c][o]

// ---------------------------------------------------------------------------
// Kernel 0: transpose W (64x64) into WT_buf.
// ---------------------------------------------------------------------------
__global__ __launch_bounds__(256) void wtrans(const float* __restrict__ W) {
  int i = blockIdx.x * 256 + threadIdx.x;
  int o = i >> 6, c = i & 63;
  WT_buf[c * CH + o] = W[o * CH + c];
}

__device__ __forceinline__ unsigned short f2bf(float f) {  // RNE to bf16
  unsigned int u = __float_as_uint(f);
  return (unsigned short)((u + 0x7FFFu + ((u >> 16) & 1u)) >> 16);
}
__device__ __forceinline__ float bf2f(unsigned short s) {
  return __uint_as_float(((unsigned int)s) << 16);
}

// ---------------------------------------------------------------------------
// Fused kernel (r10 shell + r17 panel): scores -> softmax -> single V-gather
// -> x in per-wave bf16 LDS panel -> W-projection -> out.
// 256-thread blocks (4 waves; r17's 64-thr blocks hit the per-CU workgroup
// cap), grid 2048, plain launch bounds (min-waves hints spill, r2-r13).
// Barrier-free: LDS slot [wv][c][lane] is written and re-read ONLY by the
// same thread (program-ordered, conflict-free; proven in proj r12-r15).
// bf16 x panel proven accuracy-neutral in r17 (absmax 0.0078 unchanged).
// ---------------------------------------------------------------------------
__global__ __launch_bounds__(256) void attn_fused(const float* __restrict__ Q,
                                                  const float* __restrict__ K,
                                                  const float* __restrict__ V,
                                                  const float* __restrict__ pe,
                                                  const float* __restrict__ bias,
                                                  float* __restrict__ out) {
  __shared__ unsigned short xs[4][CH][64];  // 32 KB, per-wave panels
  int tid = threadIdx.x;
  int lane = tid & 63;
  int wv = tid >> 6;

  // XCD-aware bijective swizzle (2048 % 8 == 0)
  int raw = blockIdx.x;
  int sw = (raw & 7) * 256 + (raw >> 3);
  int b = sw >> 10;
  int r = sw & 1023;
  int d = r >> 4;                                             // 0..63
  int hu = __builtin_amdgcn_readfirstlane((r & 15) * 4 + wv);  // 0..63, uniform

  size_t bbase = (size_t)b << 24;
  const float* Qb = Q + bbase;
  const float* Kb = K + bbase;
  const float* Vb = V + bbase;
  float* outb = out + bbase;

  // per-lane x-pad masks for received shuffles
  float lmL = (lane == 0) ? 0.f : 1.f;
  float lmR = (lane == 63) ? 0.f : 1.f;

  // uniform row bases (clamped) + OOB masks
  const float* krow[9];
  const float* vrow[9];
  float okf[9];
#pragma unroll
  for (int dz = 0; dz < 3; ++dz)
#pragma unroll
    for (int dy = 0; dy < 3; ++dy) {
      int rr = dz * 3 + dy;
      int zz = d + dz - 1, yy = hu + dy - 1;
      bool ok = ((unsigned)zz < 64u) & ((unsigned)yy < 64u);
      int zc = zz < 0 ? 0 : (zz > 63 ? 63 : zz);
      int yc = yy < 0 ? 0 : (yy > 63 ? 63 : yy);
      krow[rr] = Kb + zc * S2 + yc * S;
      vrow[rr] = Vb + zc * S2 + yc * S;
      okf[rr] = ok ? 1.f : 0.f;
    }
  int pos = d * S2 + hu * S + lane;

  float spe[27];  // pe part (always at own lane, unmasked)
  float sC[9], sXR[9], sXL[9];
#pragma unroll
  for (int t = 0; t < 27; ++t) spe[t] = 0.f;
#pragma unroll
  for (int rr = 0; rr < 9; ++rr) { sC[rr] = 0.f; sXR[rr] = 0.f; sXL[rr] = 0.f; }

  // ---- Phase A: scores (2 shuffles per channel) ----
#pragma unroll 4
  for (int c = 0; c < CH; ++c) {
    int coff = c * S3;
    float q = Qb[coff + pos];
    float rv[9];
#pragma unroll
    for (int rr = 0; rr < 9; ++rr) rv[rr] = krow[rr][coff + lane];
    float qR = __shfl_down(q, 1);  // q of lane+1
    float qL = __shfl_up(q, 1);    // q of lane-1
#pragma unroll
    for (int rr = 0; rr < 9; ++rr) {
      sC[rr]  = fmaf(q,  rv[rr], sC[rr]);
      sXR[rr] = fmaf(qR, rv[rr], sXR[rr]);  // belongs to lane+1's left tap
      sXL[rr] = fmaf(qL, rv[rr], sXL[rr]);  // belongs to lane-1's right tap
    }
    const float* pec = pe + c * 27;  // uniform -> scalar loads
#pragma unroll
    for (int t = 0; t < 27; ++t) spe[t] = fmaf(q, pec[t], spe[t]);
  }

  // ---- assemble the 27 tap scores (18 shuffles, once) ----
  float s[27];
#pragma unroll
  for (int rr = 0; rr < 9; ++rr) {
    float lt = __shfl_up(sXR[rr], 1);    // = sum_c q[w]*K[rr][w-1]
    float rt = __shfl_down(sXL[rr], 1);  // = sum_c q[w]*K[rr][w+1]
    s[rr * 3]     = fmaf(lt * lmL, okf[rr], spe[rr * 3]);
    s[rr * 3 + 1] = fmaf(sC[rr],   okf[rr], spe[rr * 3 + 1]);
    s[rr * 3 + 2] = fmaf(rt * lmR, okf[rr], spe[rr * 3 + 2]);
  }

  // ---- softmax over 27 taps (base-2; normalization folded into weights) ----
  const float SC = 0.125f * 1.44269504088896f;
#pragma unroll
  for (int t = 0; t < 27; ++t) s[t] *= SC;
  float m = s[0];
#pragma unroll
  for (int t = 1; t < 27; ++t) m = fmaxf(m, s[t]);
  float sum = 0.f;
#pragma unroll
  for (int t = 0; t < 27; ++t) {
    s[t] = exp2f(s[t] - m);
    sum += s[t];
  }
  float inv = 1.f / sum;

  // ---- weights: fold inv + row mask; pre-shuffle cross weights ----
  float wC[9], sLs[9], sRs[9];
#pragma unroll
  for (int rr = 0; rr < 9; ++rr) {
    float f = inv * okf[rr];  // OOB rows: V-pad = 0 -> weight 0
    float wL = s[rr * 3] * f;
    wC[rr]   = s[rr * 3 + 1] * f;
    float wR = s[rr * 3 + 2] * f;
    sLs[rr] = __shfl_down(wL, 1);  // left-tap weight of lane+1
    sRs[rr] = __shfl_up(wR, 1);    // right-tap weight of lane-1
  }

  // ---- Phase B: single V-gather -> bf16 LDS slot (own slot only) ----
#pragma unroll 2
  for (int c = 0; c < CH; ++c) {
    int coff = c * S3;
    float rv[9];
#pragma unroll
    for (int rr = 0; rr < 9; ++rr) rv[rr] = vrow[rr][coff + lane];
    float own = 0.f, cR = 0.f, cL = 0.f;
#pragma unroll
    for (int rr = 0; rr < 9; ++rr) {
      own = fmaf(wC[rr], rv[rr], own);
      cR  = fmaf(sLs[rr], rv[rr], cR);  // contribution to x of lane+1
      cL  = fmaf(sRs[rr], rv[rr], cL);  // contribution to x of lane-1
    }
    float x_c = own + __shfl_up(cR, 1) * lmL + __shfl_down(cL, 1) * lmR;
    xs[wv][c][lane] = f2bf(x_c);  // same-address slot, program-ordered
  }

  // ---- Phase P: projection from the LDS panel; o-tiled, acc[16] live ----
#pragma unroll 1
  for (int ot = 0; ot < 4; ++ot) {
    float acc[16];
#pragma unroll
    for (int j = 0; j < 16; ++j) acc[j] = 0.f;
#pragma unroll 4
    for (int c = 0; c < CH; ++c) {
      float xc = bf2f(xs[wv][c][lane]);          // re-read own slot only
      const float* wr = WT_buf + c * CH + ot * 16;  // uniform -> wide s_load
#pragma unroll
      for (int j = 0; j < 16; ++j) acc[j] = fmaf(wr[j], xc, acc[j]);
    }
#pragma unroll
    for (int j = 0; j < 16; ++j)
      outb[(ot * 16 + j) * S3 + pos] = acc[j] + bias[ot * 16 + j];
  }
}

// ---------------------------------------------------------------------------
extern "C" void kernel_launch(void* const* d_in, const int* in_sizes, int n_in,
                              void* d_out, int out_size, void* d_ws, size_t ws_size,
                              hipStream_t stream) {
  const float* Q = (const float*)d_in[0];
  const float* K = (const float*)d_in[1];
  const float* V = (const float*)d_in[2];
  const float* pe = (const float*)d_in[3];
  const float* W = (const float*)d_in[4];
  const float* bias = (const float*)d_in[5];
  float* out = (float*)d_out;

  wtrans<<<16, 256, 0, stream>>>(W);
  attn_fused<<<2048, 256, 0, stream>>>(Q, K, V, pe, bias, out);
}

// Round 19
// 220.090 us; speedup vs baseline: 1.5433x; 1.0666x over previous
//
#include <hip/hip_runtime.h>
#include <math.h>

#define CH 64
#define S 64
#define S2 (64 * 64)
#define S3 (64 * 64 * 64)

typedef short short8_t __attribute__((ext_vector_type(8)));
typedef float float4_t __attribute__((ext_vector_type(4)));

__device__ __align__(16) unsigned short WB_buf[CH * CH];  // bf16 W[o][c]

__device__ __forceinline__ unsigned short f2bf(float f) {  // RNE to bf16
  unsigned int u = __float_as_uint(f);
  return (unsigned short)((u + 0x7FFFu + ((u >> 16) & 1u)) >> 16);
}

// ---------------------------------------------------------------------------
// Kernel 0: W -> bf16 (row-major [o][c], 16B-aligned rows for A-frag loads).
// ---------------------------------------------------------------------------
__global__ __launch_bounds__(256) void wprep(const float* __restrict__ W) {
  int i = blockIdx.x * 256 + threadIdx.x;  // 4096
  WB_buf[i] = f2bf(W[i]);
}

// ---------------------------------------------------------------------------
// Fused kernel: scores -> softmax -> single V-gather -> x bf16 in per-wave
// LDS panel [p][c] -> MFMA projection -> out.  r18 shell (256 thr, grid 2048,
// plain bounds, barrier-free phases A/B) + matrix-core phase P:
//   4 p-tiles x 4 o-tiles x 2 mfma_f32_16x16x32_bf16 replaces 4096 VALU FMA.
// x panel: thread (lane=p) writes ONLY row [wv][lane][*] (program-ordered);
// phase P reads other lanes' rows -> compiler fence + threadfence_block
// (r5 lesson: same-wave DS is HW-in-order, but hipcc may hoist reads).
// Pitch 68 shorts: writes 2-way bank alias (free), b64 reads 8B-aligned.
// ---------------------------------------------------------------------------
__global__ __launch_bounds__(256) void attn_fused(const float* __restrict__ Q,
                                                  const float* __restrict__ K,
                                                  const float* __restrict__ V,
                                                  const float* __restrict__ pe,
                                                  const float* __restrict__ bias,
                                                  float* __restrict__ out) {
  __shared__ unsigned short xs[4][CH][68];  // 34816 B
  int tid = threadIdx.x;
  int lane = tid & 63;
  int wv = tid >> 6;

  // XCD-aware bijective swizzle (2048 % 8 == 0)
  int raw = blockIdx.x;
  int sw = (raw & 7) * 256 + (raw >> 3);
  int b = sw >> 10;
  int r = sw & 1023;
  int d = r >> 4;                                             // 0..63
  int hu = __builtin_amdgcn_readfirstlane((r & 15) * 4 + wv);  // 0..63, uniform

  size_t bbase = (size_t)b << 24;
  const float* Qb = Q + bbase;
  const float* Kb = K + bbase;
  const float* Vb = V + bbase;
  float* outb = out + bbase;

  // per-lane x-pad masks for received shuffles
  float lmL = (lane == 0) ? 0.f : 1.f;
  float lmR = (lane == 63) ? 0.f : 1.f;

  // uniform row bases (clamped) + OOB masks
  const float* krow[9];
  const float* vrow[9];
  float okf[9];
#pragma unroll
  for (int dz = 0; dz < 3; ++dz)
#pragma unroll
    for (int dy = 0; dy < 3; ++dy) {
      int rr = dz * 3 + dy;
      int zz = d + dz - 1, yy = hu + dy - 1;
      bool ok = ((unsigned)zz < 64u) & ((unsigned)yy < 64u);
      int zc = zz < 0 ? 0 : (zz > 63 ? 63 : zz);
      int yc = yy < 0 ? 0 : (yy > 63 ? 63 : yy);
      krow[rr] = Kb + zc * S2 + yc * S;
      vrow[rr] = Vb + zc * S2 + yc * S;
      okf[rr] = ok ? 1.f : 0.f;
    }
  int upos = d * S2 + hu * S;   // uniform row base
  int pos = upos + lane;

  float spe[27];  // pe part (always at own lane, unmasked)
  float sC[9], sXR[9], sXL[9];
#pragma unroll
  for (int t = 0; t < 27; ++t) spe[t] = 0.f;
#pragma unroll
  for (int rr = 0; rr < 9; ++rr) { sC[rr] = 0.f; sXR[rr] = 0.f; sXL[rr] = 0.f; }

  // ---- Phase A: scores (2 shuffles per channel) ----
#pragma unroll 4
  for (int c = 0; c < CH; ++c) {
    int coff = c * S3;
    float q = Qb[coff + pos];
    float rv[9];
#pragma unroll
    for (int rr = 0; rr < 9; ++rr) rv[rr] = krow[rr][coff + lane];
    float qR = __shfl_down(q, 1);  // q of lane+1
    float qL = __shfl_up(q, 1);    // q of lane-1
#pragma unroll
    for (int rr = 0; rr < 9; ++rr) {
      sC[rr]  = fmaf(q,  rv[rr], sC[rr]);
      sXR[rr] = fmaf(qR, rv[rr], sXR[rr]);  // belongs to lane+1's left tap
      sXL[rr] = fmaf(qL, rv[rr], sXL[rr]);  // belongs to lane-1's right tap
    }
    const float* pec = pe + c * 27;  // uniform -> scalar loads
#pragma unroll
    for (int t = 0; t < 27; ++t) spe[t] = fmaf(q, pec[t], spe[t]);
  }

  // ---- assemble the 27 tap scores (18 shuffles, once) ----
  float s[27];
#pragma unroll
  for (int rr = 0; rr < 9; ++rr) {
    float lt = __shfl_up(sXR[rr], 1);    // = sum_c q[w]*K[rr][w-1]
    float rt = __shfl_down(sXL[rr], 1);  // = sum_c q[w]*K[rr][w+1]
    s[rr * 3]     = fmaf(lt * lmL, okf[rr], spe[rr * 3]);
    s[rr * 3 + 1] = fmaf(sC[rr],   okf[rr], spe[rr * 3 + 1]);
    s[rr * 3 + 2] = fmaf(rt * lmR, okf[rr], spe[rr * 3 + 2]);
  }

  // ---- softmax over 27 taps (base-2; normalization folded into weights) ----
  const float SC = 0.125f * 1.44269504088896f;
#pragma unroll
  for (int t = 0; t < 27; ++t) s[t] *= SC;
  float m = s[0];
#pragma unroll
  for (int t = 1; t < 27; ++t) m = fmaxf(m, s[t]);
  float sum = 0.f;
#pragma unroll
  for (int t = 0; t < 27; ++t) {
    s[t] = exp2f(s[t] - m);
    sum += s[t];
  }
  float inv = 1.f / sum;

  // ---- weights: fold inv + row mask; pre-shuffle cross weights ----
  float wC[9], sLs[9], sRs[9];
#pragma unroll
  for (int rr = 0; rr < 9; ++rr) {
    float f = inv * okf[rr];  // OOB rows: V-pad = 0 -> weight 0
    float wL = s[rr * 3] * f;
    wC[rr]   = s[rr * 3 + 1] * f;
    float wR = s[rr * 3 + 2] * f;
    sLs[rr] = __shfl_down(wL, 1);  // left-tap weight of lane+1
    sRs[rr] = __shfl_up(wR, 1);    // right-tap weight of lane-1
  }

  // ---- Phase B: single V-gather -> bf16 pairs -> own LDS row [lane][c] ----
#pragma unroll 2
  for (int c2 = 0; c2 < CH; c2 += 2) {
    unsigned int packed = 0;
#pragma unroll
    for (int u = 0; u < 2; ++u) {
      int coff = (c2 + u) * S3;
      float rv[9];
#pragma unroll
      for (int rr = 0; rr < 9; ++rr) rv[rr] = vrow[rr][coff + lane];
      float own = 0.f, cR = 0.f, cL = 0.f;
#pragma unroll
      for (int rr = 0; rr < 9; ++rr) {
        own = fmaf(wC[rr], rv[rr], own);
        cR  = fmaf(sLs[rr], rv[rr], cR);  // contribution to x of lane+1
        cL  = fmaf(sRs[rr], rv[rr], cL);  // contribution to x of lane-1
      }
      float x_c = own + __shfl_up(cR, 1) * lmL + __shfl_down(cL, 1) * lmR;
      packed |= ((unsigned int)f2bf(x_c)) << (16 * u);
    }
    *(unsigned int*)&xs[wv][lane][c2] = packed;  // own row, program-ordered
  }

  // fence: stop the compiler hoisting cross-lane LDS reads above the writes
  __asm__ __volatile__("" ::: "memory");
  __threadfence_block();

  // ---- Phase P: MFMA projection. out[o,p] = W[o,c] x[c,p].
  //      A-frag: lane = (m=o, kchunk); B-frag: lane = (n=p, kchunk);
  //      D: col(p)=lane&15, row(o)=(lane>>4)*4+reg (HW-verified m89). ----
  {
    int n16 = lane & 15, g = lane >> 4;
    short8_t afr[8];  // [o-tile][k-chunk], 16B each, L1-cached
#pragma unroll
    for (int ot = 0; ot < 4; ++ot)
#pragma unroll
      for (int kc = 0; kc < 2; ++kc)
        afr[ot * 2 + kc] =
            *(const short8_t*)(WB_buf + (ot * 16 + n16) * CH + kc * 32 + g * 8);

#pragma unroll 1
    for (int pt = 0; pt < 4; ++pt) {
      const unsigned short* bp = &xs[wv][pt * 16 + n16][g * 8];
      union { short8_t v; uint2 h[2]; } u0, u1;
      u0.h[0] = *(const uint2*)(bp);       // c = g*8+0..3
      u0.h[1] = *(const uint2*)(bp + 4);   // c = g*8+4..7
      u1.h[0] = *(const uint2*)(bp + 32);  // c = 32+g*8+0..3
      u1.h[1] = *(const uint2*)(bp + 36);
#pragma unroll
      for (int ot = 0; ot < 4; ++ot) {
        float4_t acc = {0.f, 0.f, 0.f, 0.f};
        acc = __builtin_amdgcn_mfma_f32_16x16x32_bf16(afr[ot * 2],     u0.v, acc, 0, 0, 0);
        acc = __builtin_amdgcn_mfma_f32_16x16x32_bf16(afr[ot * 2 + 1], u1.v, acc, 0, 0, 0);
        int obase = ot * 16 + 4 * g;
        float4_t bv = *(const float4_t*)(bias + obase);  // 16B-aligned
#pragma unroll
        for (int j = 0; j < 4; ++j)
          outb[(obase + j) * S3 + upos + pt * 16 + n16] = acc[j] + bv[j];
      }
    }
  }
}

// ---------------------------------------------------------------------------
extern "C" void kernel_launch(void* const* d_in, const int* in_sizes, int n_in,
                              void* d_out, int out_size, void* d_ws, size_t ws_size,
                              hipStream_t stream) {
  const float* Q = (const float*)d_in[0];
  const float* K = (const float*)d_in[1];
  const float* V = (const float*)d_in[2];
  const float* pe = (const float*)d_in[3];
  const float* W = (const float*)d_in[4];
  const float* bias = (const float*)d_in[5];
  float* out = (float*)d_out;

  wprep<<<16, 256, 0, stream>>>(W);
  attn_fused<<<2048, 256, 0, stream>>>(Q, K, V, pe, bias, out);
}

// Round 20
// 206.828 us; speedup vs baseline: 1.6423x; 1.0641x over previous
//
#include <hip/hip_runtime.h>
#include <math.h>

#define CH 64
#define S 64
#define S2 (64 * 64)
#define S3 (64 * 64 * 64)

typedef short short8_t __attribute__((ext_vector_type(8)));
typedef float float4_t __attribute__((ext_vector_type(4)));

__device__ __align__(16) unsigned short WB_buf[CH * CH];   // bf16 W[o][c]
__device__ __align__(16) unsigned short peT_buf[32 * 64];  // bf16 peT[t][c], t>=27 zero

__device__ __forceinline__ unsigned short f2bf(float f) {  // RNE to bf16
  unsigned int u = __float_as_uint(f);
  return (unsigned short)((u + 0x7FFFu + ((u >> 16) & 1u)) >> 16);
}

// ---------------------------------------------------------------------------
// Kernel 0: W -> bf16 row-major; pe -> bf16 transposed [t][c] padded to 32 t.
// ---------------------------------------------------------------------------
__global__ __launch_bounds__(256) void wprep(const float* __restrict__ W,
                                             const float* __restrict__ pe) {
  int i = blockIdx.x * 256 + threadIdx.x;  // 0..6143
  if (i < 4096) {
    WB_buf[i] = f2bf(W[i]);
  } else {
    int j = i - 4096;  // 0..2047
    int t = j >> 6, c = j & 63;
    peT_buf[t * 64 + c] = (t < 27) ? f2bf(pe[c * 27 + t]) : (unsigned short)0;
  }
}

// ---------------------------------------------------------------------------
// Fused kernel. One wave per (b,d,h) row; lane = w. 256-thr blocks, grid 2048.
// Phase A: QK tap scores (27 accs) + pack Q->bf16 into LDS panel [p][c].
// pe-MFMA: spe = peT x Q  (16 mfma), C-frags redistributed via the SAME LDS
//   region viewed as float[64][33] ([p][t]; nt's writes only touch rows its
//   own B-frag reads already consumed).
// softmax -> weights -> Phase B: V-gather -> x bf16 panel (own slot).
// Phase P: out = W x  (32 mfma) + bias. All frag layouts HW-validated (r19).
// Plain launch bounds (hints spill, r2-r13); barrier-free (per-wave panels,
// same-wave DS is HW-in-order; compiler fenced at cross-lane handoffs).
// ---------------------------------------------------------------------------
__global__ __launch_bounds__(256) void attn_fused(const float* __restrict__ Q,
                                                  const float* __restrict__ K,
                                                  const float* __restrict__ V,
                                                  const float* __restrict__ bias,
                                                  float* __restrict__ out) {
  __shared__ unsigned short xs[4][CH][68];  // 34816 B (time-shared: Q/spe/x)
  int tid = threadIdx.x;
  int lane = tid & 63;
  int wv = tid >> 6;

  // XCD-aware bijective swizzle (2048 % 8 == 0)
  int raw = blockIdx.x;
  int sw = (raw & 7) * 256 + (raw >> 3);
  int b = sw >> 10;
  int r = sw & 1023;
  int d = r >> 4;                                             // 0..63
  int hu = __builtin_amdgcn_readfirstlane((r & 15) * 4 + wv);  // 0..63, uniform

  size_t bbase = (size_t)b << 24;
  const float* Qb = Q + bbase;
  const float* Kb = K + bbase;
  const float* Vb = V + bbase;
  float* outb = out + bbase;

  float lmL = (lane == 0) ? 0.f : 1.f;
  float lmR = (lane == 63) ? 0.f : 1.f;

  // uniform row offsets (clamped) + OOB masks; K pointers now, V later
  int rowoff[9];
  float okf[9];
  const float* krow[9];
#pragma unroll
  for (int dz = 0; dz < 3; ++dz)
#pragma unroll
    for (int dy = 0; dy < 3; ++dy) {
      int rr = dz * 3 + dy;
      int zz = d + dz - 1, yy = hu + dy - 1;
      bool ok = ((unsigned)zz < 64u) & ((unsigned)yy < 64u);
      int zc = zz < 0 ? 0 : (zz > 63 ? 63 : zz);
      int yc = yy < 0 ? 0 : (yy > 63 ? 63 : yy);
      rowoff[rr] = __builtin_amdgcn_readfirstlane(zc * S2 + yc * S);
      krow[rr] = Kb + rowoff[rr];
      okf[rr] = ok ? 1.f : 0.f;
    }
  int upos = d * S2 + hu * S;
  int pos = upos + lane;

  float sC[9], sXR[9], sXL[9];
#pragma unroll
  for (int rr = 0; rr < 9; ++rr) { sC[rr] = 0.f; sXR[rr] = 0.f; sXL[rr] = 0.f; }

  // ---- Phase A: QK tap scores + Q->bf16 LDS pack (own row [lane][c]) ----
#pragma unroll 2
  for (int c2 = 0; c2 < CH; c2 += 2) {
    unsigned int qpack = 0;
#pragma unroll
    for (int u = 0; u < 2; ++u) {
      int coff = (c2 + u) * S3;
      float q = Qb[coff + pos];
      float rv[9];
#pragma unroll
      for (int rr = 0; rr < 9; ++rr) rv[rr] = krow[rr][coff + lane];
      float qR = __shfl_down(q, 1);
      float qL = __shfl_up(q, 1);
#pragma unroll
      for (int rr = 0; rr < 9; ++rr) {
        sC[rr]  = fmaf(q,  rv[rr], sC[rr]);
        sXR[rr] = fmaf(qR, rv[rr], sXR[rr]);  // lane+1's left tap
        sXL[rr] = fmaf(qL, rv[rr], sXL[rr]);  // lane-1's right tap
      }
      qpack |= ((unsigned int)f2bf(q)) << (16 * u);
    }
    *(unsigned int*)&xs[wv][lane][c2] = qpack;  // own slot, program-ordered
  }

  __asm__ __volatile__("" ::: "memory");
  __threadfence_block();

  // ---- pe-MFMA: spe[t][p] = peT[t][c] * Qbf[c][p]; redistribute via LDS ----
  float spe[27];
  {
    int n16 = lane & 15, g = lane >> 4;
    short8_t pfr[4];  // [mt][kc]
#pragma unroll
    for (int mt = 0; mt < 2; ++mt)
#pragma unroll
      for (int kc = 0; kc < 2; ++kc)
        pfr[mt * 2 + kc] =
            *(const short8_t*)(peT_buf + (mt * 16 + n16) * 64 + kc * 32 + g * 8);
    float* spf = (float*)&xs[wv][0][0];  // view: float[64][33] ([p][t])
#pragma unroll 1
    for (int nt = 0; nt < 4; ++nt) {
      const unsigned short* bp = &xs[wv][nt * 16 + n16][g * 8];
      union { short8_t v; uint2 h[2]; } u0, u1;
      u0.h[0] = *(const uint2*)(bp);
      u0.h[1] = *(const uint2*)(bp + 4);
      u1.h[0] = *(const uint2*)(bp + 32);
      u1.h[1] = *(const uint2*)(bp + 36);
#pragma unroll
      for (int mt = 0; mt < 2; ++mt) {
        float4_t acc = {0.f, 0.f, 0.f, 0.f};
        acc = __builtin_amdgcn_mfma_f32_16x16x32_bf16(pfr[mt * 2],     u0.v, acc, 0, 0, 0);
        acc = __builtin_amdgcn_mfma_f32_16x16x32_bf16(pfr[mt * 2 + 1], u1.v, acc, 0, 0, 0);
        // D: col(p)=n16, row(t)=mt*16+g*4+j -> write [p][t] rows this nt owns
#pragma unroll
        for (int j = 0; j < 4; ++j)
          spf[(nt * 16 + n16) * 33 + mt * 16 + g * 4 + j] = acc[j];
      }
    }
    __asm__ __volatile__("" ::: "memory");
    __threadfence_block();
#pragma unroll
    for (int t = 0; t < 27; ++t) spe[t] = spf[lane * 33 + t];  // own position row
  }

  // ---- assemble 27 tap scores (18 shuffles) ----
  float s[27];
#pragma unroll
  for (int rr = 0; rr < 9; ++rr) {
    float lt = __shfl_up(sXR[rr], 1);
    float rt = __shfl_down(sXL[rr], 1);
    s[rr * 3]     = fmaf(lt * lmL, okf[rr], spe[rr * 3]);
    s[rr * 3 + 1] = fmaf(sC[rr],   okf[rr], spe[rr * 3 + 1]);
    s[rr * 3 + 2] = fmaf(rt * lmR, okf[rr], spe[rr * 3 + 2]);
  }

  // ---- softmax (base-2; normalization folded into weights) ----
  const float SC = 0.125f * 1.44269504088896f;
#pragma unroll
  for (int t = 0; t < 27; ++t) s[t] *= SC;
  float m = s[0];
#pragma unroll
  for (int t = 1; t < 27; ++t) m = fmaxf(m, s[t]);
  float sum = 0.f;
#pragma unroll
  for (int t = 0; t < 27; ++t) {
    s[t] = exp2f(s[t] - m);
    sum += s[t];
  }
  float inv = 1.f / sum;

  // ---- weights + V row pointers (deferred live range) ----
  float wC[9], sLs[9], sRs[9];
  const float* vrow[9];
#pragma unroll
  for (int rr = 0; rr < 9; ++rr) {
    vrow[rr] = Vb + rowoff[rr];
    float f = inv * okf[rr];
    float wL = s[rr * 3] * f;
    wC[rr]   = s[rr * 3 + 1] * f;
    float wR = s[rr * 3 + 2] * f;
    sLs[rr] = __shfl_down(wL, 1);
    sRs[rr] = __shfl_up(wR, 1);
  }

  __asm__ __volatile__("" ::: "memory");
  __threadfence_block();

  // ---- Phase B: V-gather -> x bf16 pairs -> own LDS row [lane][c] ----
#pragma unroll 2
  for (int c2 = 0; c2 < CH; c2 += 2) {
    unsigned int packed = 0;
#pragma unroll
    for (int u = 0; u < 2; ++u) {
      int coff = (c2 + u) * S3;
      float rv[9];
#pragma unroll
      for (int rr = 0; rr < 9; ++rr) rv[rr] = vrow[rr][coff + lane];
      float own = 0.f, cR = 0.f, cL = 0.f;
#pragma unroll
      for (int rr = 0; rr < 9; ++rr) {
        own = fmaf(wC[rr], rv[rr], own);
        cR  = fmaf(sLs[rr], rv[rr], cR);
        cL  = fmaf(sRs[rr], rv[rr], cL);
      }
      float x_c = own + __shfl_up(cR, 1) * lmL + __shfl_down(cL, 1) * lmR;
      packed |= ((unsigned int)f2bf(x_c)) << (16 * u);
    }
    *(unsigned int*)&xs[wv][lane][c2] = packed;
  }

  __asm__ __volatile__("" ::: "memory");
  __threadfence_block();

  // ---- Phase P: MFMA projection out = W x + bias (layouts r19-verified) ----
  {
    int n16 = lane & 15, g = lane >> 4;
    short8_t afr[8];  // [o-tile][k-chunk]
#pragma unroll
    for (int ot = 0; ot < 4; ++ot)
#pragma unroll
      for (int kc = 0; kc < 2; ++kc)
        afr[ot * 2 + kc] =
            *(const short8_t*)(WB_buf + (ot * 16 + n16) * CH + kc * 32 + g * 8);

#pragma unroll 1
    for (int pt = 0; pt < 4; ++pt) {
      const unsigned short* bp = &xs[wv][pt * 16 + n16][g * 8];
      union { short8_t v; uint2 h[2]; } u0, u1;
      u0.h[0] = *(const uint2*)(bp);
      u0.h[1] = *(const uint2*)(bp + 4);
      u1.h[0] = *(const uint2*)(bp + 32);
      u1.h[1] = *(const uint2*)(bp + 36);
#pragma unroll
      for (int ot = 0; ot < 4; ++ot) {
        float4_t acc = {0.f, 0.f, 0.f, 0.f};
        acc = __builtin_amdgcn_mfma_f32_16x16x32_bf16(afr[ot * 2],     u0.v, acc, 0, 0, 0);
        acc = __builtin_amdgcn_mfma_f32_16x16x32_bf16(afr[ot * 2 + 1], u1.v, acc, 0, 0, 0);
        int obase = ot * 16 + 4 * g;
        float4_t bv = *(const float4_t*)(bias + obase);
#pragma unroll
        for (int j = 0; j < 4; ++j)
          outb[(obase + j) * S3 + upos + pt * 16 + n16] = acc[j] + bv[j];
      }
    }
  }
}

// ---------------------------------------------------------------------------
extern "C" void kernel_launch(void* const* d_in, const int* in_sizes, int n_in,
                              void* d_out, int out_size, void* d_ws, size_t ws_size,
                              hipStream_t stream) {
  const float* Q = (const float*)d_in[0];
  const float* K = (const float*)d_in[1];
  const float* V = (const float*)d_in[2];
  const float* pe = (const float*)d_in[3];
  const float* W = (const float*)d_in[4];
  const float* bias = (const float*)d_in[5];
  float* out = (float*)d_out;

  wprep<<<24, 256, 0, stream>>>(W, pe);
  attn_fused<<<2048, 256, 0, stream>>>(Q, K, V, bias, out);
}

// Round 21
// 203.067 us; speedup vs baseline: 1.6727x; 1.0185x over previous
//
#include <hip/hip_runtime.h>
#include <math.h>

#define CH 64
#define S 64
#define S2 (64 * 64)
#define S3 (64 * 64 * 64)

typedef short short8_t __attribute__((ext_vector_type(8)));
typedef float float4_t __attribute__((ext_vector_type(4)));

__device__ __align__(16) unsigned short WB_buf[CH * CH];   // bf16 W[o][c]
__device__ __align__(16) unsigned short peT_buf[32 * 64];  // bf16 peT[t][c], t>=27 zero

__device__ __forceinline__ unsigned short f2bf(float f) {  // RNE to bf16
  unsigned int u = __float_as_uint(f);
  return (unsigned short)((u + 0x7FFFu + ((u >> 16) & 1u)) >> 16);
}

// ---------------------------------------------------------------------------
// Kernel 0: W -> bf16 row-major; pe -> bf16 transposed [t][c] padded to 32 t.
// ---------------------------------------------------------------------------
__global__ __launch_bounds__(256) void wprep(const float* __restrict__ W,
                                             const float* __restrict__ pe) {
  int i = blockIdx.x * 256 + threadIdx.x;  // 0..6143
  if (i < 4096) {
    WB_buf[i] = f2bf(W[i]);
  } else {
    int j = i - 4096;  // 0..2047
    int t = j >> 6, c = j & 63;
    peT_buf[t * 64 + c] = (t < 27) ? f2bf(pe[c * 27 + t]) : (unsigned short)0;
  }
}

// ---------------------------------------------------------------------------
// Fused kernel (r20 + two register cuts):
//  - spe[27] eliminated: tap assembly reads the pe-MFMA result directly from
//    the LDS float view (peak live at the A/assembly boundary 54 -> 27).
//  - Phase P is ot-outer/pt-inner, unroll 1 both: only 8+8 frag regs live
//    (was afr[8]=32 hoisted); B-frags re-read from LDS per iteration (cheap).
// Everything else identical to r20 (HW-validated frag layouts, fences at
// cross-lane handoffs, plain launch bounds, barrier-free per-wave panels).
// ---------------------------------------------------------------------------
__global__ __launch_bounds__(256) void attn_fused(const float* __restrict__ Q,
                                                  const float* __restrict__ K,
                                                  const float* __restrict__ V,
                                                  const float* __restrict__ bias,
                                                  float* __restrict__ out) {
  __shared__ unsigned short xs[4][CH][68];  // 34816 B (time-shared: Q/spe/x)
  int tid = threadIdx.x;
  int lane = tid & 63;
  int wv = tid >> 6;

  // XCD-aware bijective swizzle (2048 % 8 == 0)
  int raw = blockIdx.x;
  int sw = (raw & 7) * 256 + (raw >> 3);
  int b = sw >> 10;
  int r = sw & 1023;
  int d = r >> 4;                                             // 0..63
  int hu = __builtin_amdgcn_readfirstlane((r & 15) * 4 + wv);  // 0..63, uniform

  size_t bbase = (size_t)b << 24;
  const float* Qb = Q + bbase;
  const float* Kb = K + bbase;
  const float* Vb = V + bbase;
  float* outb = out + bbase;

  float lmL = (lane == 0) ? 0.f : 1.f;
  float lmR = (lane == 63) ? 0.f : 1.f;

  // uniform row offsets (clamped) + OOB masks; K pointers now, V later
  int rowoff[9];
  float okf[9];
  const float* krow[9];
#pragma unroll
  for (int dz = 0; dz < 3; ++dz)
#pragma unroll
    for (int dy = 0; dy < 3; ++dy) {
      int rr = dz * 3 + dy;
      int zz = d + dz - 1, yy = hu + dy - 1;
      bool ok = ((unsigned)zz < 64u) & ((unsigned)yy < 64u);
      int zc = zz < 0 ? 0 : (zz > 63 ? 63 : zz);
      int yc = yy < 0 ? 0 : (yy > 63 ? 63 : yy);
      rowoff[rr] = __builtin_amdgcn_readfirstlane(zc * S2 + yc * S);
      krow[rr] = Kb + rowoff[rr];
      okf[rr] = ok ? 1.f : 0.f;
    }
  int upos = d * S2 + hu * S;
  int pos = upos + lane;

  float sC[9], sXR[9], sXL[9];
#pragma unroll
  for (int rr = 0; rr < 9; ++rr) { sC[rr] = 0.f; sXR[rr] = 0.f; sXL[rr] = 0.f; }

  // ---- Phase A: QK tap scores + Q->bf16 LDS pack (own row [lane][c]) ----
#pragma unroll 2
  for (int c2 = 0; c2 < CH; c2 += 2) {
    unsigned int qpack = 0;
#pragma unroll
    for (int u = 0; u < 2; ++u) {
      int coff = (c2 + u) * S3;
      float q = Qb[coff + pos];
      float rv[9];
#pragma unroll
      for (int rr = 0; rr < 9; ++rr) rv[rr] = krow[rr][coff + lane];
      float qR = __shfl_down(q, 1);
      float qL = __shfl_up(q, 1);
#pragma unroll
      for (int rr = 0; rr < 9; ++rr) {
        sC[rr]  = fmaf(q,  rv[rr], sC[rr]);
        sXR[rr] = fmaf(qR, rv[rr], sXR[rr]);  // lane+1's left tap
        sXL[rr] = fmaf(qL, rv[rr], sXL[rr]);  // lane-1's right tap
      }
      qpack |= ((unsigned int)f2bf(q)) << (16 * u);
    }
    *(unsigned int*)&xs[wv][lane][c2] = qpack;  // own slot, program-ordered
  }

  __asm__ __volatile__("" ::: "memory");
  __threadfence_block();

  // ---- pe-MFMA: spe[t][p] = peT[t][c] * Qbf[c][p] -> LDS float[64][33] ----
  {
    int n16 = lane & 15, g = lane >> 4;
    short8_t pfr[4];  // [mt][kc]
#pragma unroll
    for (int mt = 0; mt < 2; ++mt)
#pragma unroll
      for (int kc = 0; kc < 2; ++kc)
        pfr[mt * 2 + kc] =
            *(const short8_t*)(peT_buf + (mt * 16 + n16) * 64 + kc * 32 + g * 8);
    float* spf = (float*)&xs[wv][0][0];  // view: float[64][33] ([p][t])
#pragma unroll 1
    for (int nt = 0; nt < 4; ++nt) {
      const unsigned short* bp = &xs[wv][nt * 16 + n16][g * 8];
      union { short8_t v; uint2 h[2]; } u0, u1;
      u0.h[0] = *(const uint2*)(bp);
      u0.h[1] = *(const uint2*)(bp + 4);
      u1.h[0] = *(const uint2*)(bp + 32);
      u1.h[1] = *(const uint2*)(bp + 36);
#pragma unroll
      for (int mt = 0; mt < 2; ++mt) {
        float4_t acc = {0.f, 0.f, 0.f, 0.f};
        acc = __builtin_amdgcn_mfma_f32_16x16x32_bf16(pfr[mt * 2],     u0.v, acc, 0, 0, 0);
        acc = __builtin_amdgcn_mfma_f32_16x16x32_bf16(pfr[mt * 2 + 1], u1.v, acc, 0, 0, 0);
        // D: col(p)=n16, row(t)=mt*16+g*4+j -> write [p][t] rows this nt owns
#pragma unroll
        for (int j = 0; j < 4; ++j)
          spf[(nt * 16 + n16) * 33 + mt * 16 + g * 4 + j] = acc[j];
      }
    }
  }

  __asm__ __volatile__("" ::: "memory");
  __threadfence_block();

  // ---- assemble 27 tap scores; pe part read STRAIGHT from LDS (no spe[]) ----
  float s[27];
  {
    const float* spf = (const float*)&xs[wv][0][0];
    int sbase = lane * 33;
#pragma unroll
    for (int rr = 0; rr < 9; ++rr) {
      float lt = __shfl_up(sXR[rr], 1);
      float rt = __shfl_down(sXL[rr], 1);
      s[rr * 3]     = fmaf(sC[rr],   okf[rr], 0.f);  // placeholder order fix below
      s[rr * 3]     = fmaf(lt * lmL, okf[rr], spf[sbase + rr * 3]);
      s[rr * 3 + 1] = fmaf(sC[rr],   okf[rr], spf[sbase + rr * 3 + 1]);
      s[rr * 3 + 2] = fmaf(rt * lmR, okf[rr], spf[sbase + rr * 3 + 2]);
    }
  }

  // ---- softmax (base-2; normalization folded into weights) ----
  const float SC = 0.125f * 1.44269504088896f;
#pragma unroll
  for (int t = 0; t < 27; ++t) s[t] *= SC;
  float m = s[0];
#pragma unroll
  for (int t = 1; t < 27; ++t) m = fmaxf(m, s[t]);
  float sum = 0.f;
#pragma unroll
  for (int t = 0; t < 27; ++t) {
    s[t] = exp2f(s[t] - m);
    sum += s[t];
  }
  float inv = 1.f / sum;

  // ---- weights + V row pointers (deferred live range) ----
  float wC[9], sLs[9], sRs[9];
  const float* vrow[9];
#pragma unroll
  for (int rr = 0; rr < 9; ++rr) {
    vrow[rr] = Vb + rowoff[rr];
    float f = inv * okf[rr];
    float wL = s[rr * 3] * f;
    wC[rr]   = s[rr * 3 + 1] * f;
    float wR = s[rr * 3 + 2] * f;
    sLs[rr] = __shfl_down(wL, 1);
    sRs[rr] = __shfl_up(wR, 1);
  }

  __asm__ __volatile__("" ::: "memory");
  __threadfence_block();

  // ---- Phase B: V-gather -> x bf16 pairs -> own LDS row [lane][c] ----
#pragma unroll 2
  for (int c2 = 0; c2 < CH; c2 += 2) {
    unsigned int packed = 0;
#pragma unroll
    for (int u = 0; u < 2; ++u) {
      int coff = (c2 + u) * S3;
      float rv[9];
#pragma unroll
      for (int rr = 0; rr < 9; ++rr) rv[rr] = vrow[rr][coff + lane];
      float own = 0.f, cR = 0.f, cL = 0.f;
#pragma unroll
      for (int rr = 0; rr < 9; ++rr) {
        own = fmaf(wC[rr], rv[rr], own);
        cR  = fmaf(sLs[rr], rv[rr], cR);
        cL  = fmaf(sRs[rr], rv[rr], cL);
      }
      float x_c = own + __shfl_up(cR, 1) * lmL + __shfl_down(cL, 1) * lmR;
      packed |= ((unsigned int)f2bf(x_c)) << (16 * u);
    }
    *(unsigned int*)&xs[wv][lane][c2] = packed;
  }

  __asm__ __volatile__("" ::: "memory");
  __threadfence_block();

  // ---- Phase P: MFMA projection, ot-outer/pt-inner, minimal live frags ----
  {
    int n16 = lane & 15, g = lane >> 4;
#pragma unroll 1
    for (int ot = 0; ot < 4; ++ot) {
      short8_t a0 = *(const short8_t*)(WB_buf + (ot * 16 + n16) * CH + g * 8);
      short8_t a1 = *(const short8_t*)(WB_buf + (ot * 16 + n16) * CH + 32 + g * 8);
      int obase = ot * 16 + 4 * g;
      float4_t bv = *(const float4_t*)(bias + obase);
#pragma unroll 1
      for (int pt = 0; pt < 4; ++pt) {
        const unsigned short* bp = &xs[wv][pt * 16 + n16][g * 8];
        union { short8_t v; uint2 h[2]; } u0, u1;
        u0.h[0] = *(const uint2*)(bp);
        u0.h[1] = *(const uint2*)(bp + 4);
        u1.h[0] = *(const uint2*)(bp + 32);
        u1.h[1] = *(const uint2*)(bp + 36);
        float4_t acc = {0.f, 0.f, 0.f, 0.f};
        acc = __builtin_amdgcn_mfma_f32_16x16x32_bf16(a0, u0.v, acc, 0, 0, 0);
        acc = __builtin_amdgcn_mfma_f32_16x16x32_bf16(a1, u1.v, acc, 0, 0, 0);
#pragma unroll
        for (int j = 0; j < 4; ++j)
          outb[(obase + j) * S3 + upos + pt * 16 + n16] = acc[j] + bv[j];
      }
    }
  }
}

// ---------------------------------------------------------------------------
extern "C" void kernel_launch(void* const* d_in, const int* in_sizes, int n_in,
                              void* d_out, int out_size, void* d_ws, size_t ws_size,
                              hipStream_t stream) {
  const float* Q = (const float*)d_in[0];
  const float* K = (const float*)d_in[1];
  const float* V = (const float*)d_in[2];
  const float* pe = (const float*)d_in[3];
  const float* W = (const float*)d_in[4];
  const float* bias = (const float*)d_in[5];
  float* out = (float*)d_out;

  wprep<<<24, 256, 0, stream>>>(W, pe);
  attn_fused<<<2048, 256, 0, stream>>>(Q, K, V, bias, out);
}